// Round 5
// baseline (35.782 us; speedup 1.0000x reference)
//
#include <hip/hip_runtime.h>
#include <hip/hip_bf16.h>

typedef short bf16x8 __attribute__((ext_vector_type(8)));
typedef float f32x16 __attribute__((ext_vector_type(16)));
typedef unsigned short u16;

#define B 128
#define LQ 32
#define LK 128
#define D 128
#define YPB 4

// ws layout:
//   lbf: fragment-ordered l, [x][ks(8)][hh(2)][rr(32)] x 16B = 8 KB/x, 1 MiB
//   rbf: fragment-ordered r, [y][mj(4)][ks(8)][hh(2)][rr(32)] x 16B = 32 KB/y, 4 MiB
//   sims: B*B f32, 64 KiB
// Fragment semantics (verified by rounds 3/4 passing): for 32x32x16 MFMA,
// lane = hh*32 + rr holds 8 elems with k = ks*16 + hh*8 + e; rr = A-row/B-col.

static __device__ inline u16 f2bf_rne(float f) {
  union { float f; unsigned u; } v; v.f = f;
  unsigned r = v.u + 0x7fffu + ((v.u >> 16) & 1u);
  return (u16)(r >> 16);
}

// One wave per row. Normalize, cast to bf16, store in MFMA-fragment order.
// Lane l holds d = 2l, 2l+1 -> chunk ks = l>>3, hh = (l>>2)&1, byte (l&3)*4.
__global__ __launch_bounds__(256) void normalize_kernel(
    const float* __restrict__ left, const float* __restrict__ right,
    char* __restrict__ lbf, char* __restrict__ rbf) {
  int wave = (blockIdx.x * blockDim.x + threadIdx.x) >> 6;
  int lane = threadIdx.x & 63;
  const int n_l = B * LQ;
  const float* src; char* dst;
  if (wave < n_l) {
    int x = wave >> 5, i = wave & 31;
    src = left + (size_t)wave * D;
    dst = lbf + x * 8192 + i * 16;
  } else {
    int row = wave - n_l;
    int y = row >> 7, j = row & 127;
    src = right + (size_t)row * D;
    dst = rbf + y * 32768 + (j >> 5) * 8192 + (j & 31) * 16;
  }
  float2 v = *reinterpret_cast<const float2*>(src + lane * 2);
  float ss = v.x * v.x + v.y * v.y;
#pragma unroll
  for (int off = 1; off < 64; off <<= 1) ss += __shfl_xor(ss, off);
  float inv = 1.0f / fmaxf(sqrtf(ss), 1e-12f);
  unsigned packed = (unsigned)f2bf_rne(v.x * inv) |
                    ((unsigned)f2bf_rne(v.y * inv) << 16);
  *reinterpret_cast<unsigned*>(
      dst + (lane >> 3) * 1024 + ((lane >> 2) & 1) * 512 + (lane & 3) * 4) = packed;
}

// Per (x,y): T[j][i] = sum_k r[y][j][k]*l[x][i][k] via 32x32x16 bf16 MFMA;
// sim[x][y] = sum_i max_j T. No LDS/barriers: fragment-ordered inputs make
// every A/B load a contiguous 1KB wave load from L1/L2. 2-deep ping-pong
// prefetch (pA/pB), fully unrolled. Grid 16 xg x 32 yg = 512 blocks,
// 4 waves (wave = 2 x's), 4 y per block.
__global__ __launch_bounds__(256, 2) void maxsim_kernel(
    const char* __restrict__ lbf, const char* __restrict__ rbf,
    float* __restrict__ sims) {
  const int lane = threadIdx.x & 63;
  const int wv   = threadIdx.x >> 6;   // 0..3
  const int xg   = blockIdx.x >> 5;    // 0..15
  const int yg   = blockIdx.x & 31;    // 0..31
  const int x0   = xg * 8 + wv * 2;
  const int lane16 = lane * 16;

  // B fragments for 2 x's: 16 contiguous 1KB loads.
  bf16x8 bfr[2][8];
#pragma unroll
  for (int xi = 0; xi < 2; ++xi)
#pragma unroll
    for (int ks = 0; ks < 8; ++ks)
      bfr[xi][ks] = *reinterpret_cast<const bf16x8*>(
          lbf + (x0 + xi) * 8192 + ks * 1024 + lane16);

  f32x16 z;
#pragma unroll
  for (int t = 0; t < 16; ++t) z[t] = 0.f;

  const char* rb0 = rbf + (size_t)(yg * YPB) * 32768;

#define LOADA(dst, s_next)                                                   \
  {                                                                          \
    const char* nb = rb0 + ((s_next) >> 2) * 32768 + ((s_next) & 3) * 8192;  \
    _Pragma("unroll")                                                        \
    for (int ks = 0; ks < 8; ++ks)                                           \
      dst[ks] = *reinterpret_cast<const bf16x8*>(nb + ks * 1024 + lane16);   \
  }

#define MFMAB(srcA)                                                          \
  __builtin_amdgcn_s_setprio(1);                                             \
  a0 = __builtin_amdgcn_mfma_f32_32x32x16_bf16(srcA[0], bfr[0][0], z, 0, 0, 0); \
  a1 = __builtin_amdgcn_mfma_f32_32x32x16_bf16(srcA[0], bfr[1][0], z, 0, 0, 0); \
  _Pragma("unroll")                                                          \
  for (int ks = 1; ks < 8; ++ks) {                                           \
    a0 = __builtin_amdgcn_mfma_f32_32x32x16_bf16(srcA[ks], bfr[0][ks], a0, 0, 0, 0); \
    a1 = __builtin_amdgcn_mfma_f32_32x32x16_bf16(srcA[ks], bfr[1][ks], a1, 0, 0, 0); \
  }                                                                          \
  __builtin_amdgcn_s_setprio(0);

  bf16x8 pA[8], pB[8];
  LOADA(pA, 0);

#pragma unroll
  for (int yy = 0; yy < YPB; ++yy) {
    float cm0 = -3.0e38f, cm1 = -3.0e38f;
#pragma unroll
    for (int mj = 0; mj < 4; ++mj) {
      const int s = yy * 4 + mj;        // compile-time after unroll
      f32x16 a0, a1;
      if ((s & 1) == 0) {
        if (s < 15) LOADA(pB, s + 1);
        MFMAB(pA);
      } else {
        if (s < 15) LOADA(pA, s + 1);
        MFMAB(pB);
      }
      // fold 16 rows into running column max
#pragma unroll
      for (int t = 0; t < 16; t += 4) {
        cm0 = fmaxf(cm0, fmaxf(fmaxf(a0[t], a0[t + 1]), fmaxf(a0[t + 2], a0[t + 3])));
        cm1 = fmaxf(cm1, fmaxf(fmaxf(a1[t], a1[t + 1]), fmaxf(a1[t + 2], a1[t + 3])));
      }
    }
    // lanes l, l+32 hold complementary row sets -> xor32 completes max_j;
    // then butterfly-sum the 32 column-maxes (i = lane&31).
    cm0 = fmaxf(cm0, __shfl_xor(cm0, 32));
    cm1 = fmaxf(cm1, __shfl_xor(cm1, 32));
#pragma unroll
    for (int off = 1; off <= 16; off <<= 1) {
      cm0 += __shfl_xor(cm0, off);
      cm1 += __shfl_xor(cm1, off);
    }
    if (lane == 0) {
      const int y = yg * YPB + yy;
      sims[(x0 + 0) * B + y] = cm0;
      sims[(x0 + 1) * B + y] = cm1;
    }
  }
#undef LOADA
#undef MFMAB
}

// log-softmax + CE. 1 block, 1024 threads = 16 waves; wave w -> rows w*8..+7.
__global__ __launch_bounds__(1024) void loss_kernel(
    const float* __restrict__ sims, const float* __restrict__ logit_scale,
    const int* __restrict__ pos_idx, float* __restrict__ out) {
  __shared__ float red[16];
  const int lane = threadIdx.x & 63;
  const int wv   = threadIdx.x >> 6;
  const float scale = expf(logit_scale[0]);
  float local = 0.f;
#pragma unroll
  for (int rr = 0; rr < 8; ++rr) {
    const int x = wv * 8 + rr;
    const float* row = sims + x * B;
    float a = row[lane], b2 = row[64 + lane];
    float m = fmaxf(a, b2);
#pragma unroll
    for (int off = 1; off < 64; off <<= 1) m = fmaxf(m, __shfl_xor(m, off));
    float ml = scale * m;
    float e = expf(scale * a - ml) + expf(scale * b2 - ml);
#pragma unroll
    for (int off = 1; off < 64; off <<= 1) e += __shfl_xor(e, off);
    int pos = pos_idx[x];
    float pv = __shfl(pos < 64 ? a : b2, pos & 63);
    local += -(scale * pv - ml - logf(e));
  }
  if (lane == 0) red[wv] = local;
  __syncthreads();
  if (threadIdx.x == 0) {
    float t = 0.f;
#pragma unroll
    for (int i = 0; i < 16; ++i) t += red[i];
    out[0] = t / (float)B;
  }
}

extern "C" void kernel_launch(void* const* d_in, const int* in_sizes, int n_in,
                              void* d_out, int out_size, void* d_ws, size_t ws_size,
                              hipStream_t stream) {
  const float* left  = (const float*)d_in[0];
  const float* right = (const float*)d_in[1];
  const float* ls    = (const float*)d_in[2];
  const int*   pos   = (const int*)d_in[3];
  float* out = (float*)d_out;

  char* ws  = (char*)d_ws;
  char* lbf = ws;                                   // 1 MiB
  char* rbf = ws + (size_t)B * LQ * D * 2;          // 4 MiB
  float* sims = (float*)(ws + (size_t)B * LQ * D * 2 + (size_t)B * LK * D * 2);

  int waves = B * LQ + B * LK;  // 20480 rows
  normalize_kernel<<<waves / 4, 256, 0, stream>>>(left, right, lbf, rbf);
  maxsim_kernel<<<512, 256, 0, stream>>>(lbf, rbf, sims);
  loss_kernel<<<1, 1024, 0, stream>>>(sims, ls, pos, out);
}